// Round 1
// baseline (234.489 us; speedup 1.0000x reference)
//
#include <hip/hip_runtime.h>
#include <cstdint>

#define BN 4
#define CIN 256
#define HALFC 128
#define HW 4096
#define SPLIT 4
#define JT 64
#define JITERS (HW / SPLIT / JT)   // 16

typedef float  floatx4 __attribute__((ext_vector_type(4)));
typedef short  shortx8 __attribute__((ext_vector_type(8)));

#if __has_builtin(__builtin_amdgcn_exp2f)
#define EXP2F(x) __builtin_amdgcn_exp2f(x)
#else
#define EXP2F(x) exp2f(x)
#endif
#define L2E 1.44269504088896f

__device__ __forceinline__ unsigned short f2bf(float f) {
  unsigned u = __float_as_uint(f);
  u += 0x7FFFu + ((u >> 16) & 1u);   // round-to-nearest-even
  return (unsigned short)(u >> 16);
}

__device__ __forceinline__ void async16(const void* g, void* l) {
  __builtin_amdgcn_global_load_lds((const __attribute__((address_space(1))) void*)g,
                                   (__attribute__((address_space(3))) void*)l, 16, 0, 0);
}

// ---------------- K1: QKV projection (fp32)  n[b][384][4096] = W(384x256) * x ----------
// grid: b(4) x stripe(4) x cot(24) = 384 blocks, 256 thr. thread: 16 co x 4 pixels.
__global__ __launch_bounds__(256) void k_proj(const float* __restrict__ x,
    const float* __restrict__ w1, const float* __restrict__ w2,
    const float* __restrict__ w3, float* __restrict__ nbuf) {
  __shared__ float wt[16 * 256];
  int bid = blockIdx.x;
  int cot = bid % 24;
  int stripe = (bid / 24) & 3;
  int b = bid / 96;
  int t = threadIdx.x;
  int co0 = cot * 16;
  const float* wsrc = (co0 < 128) ? (w1 + (size_t)co0 * 256)
                    : (co0 < 256) ? (w2 + (size_t)(co0 - 128) * 256)
                                  : (w3 + (size_t)(co0 - 256) * 256);
#pragma unroll
  for (int k = 0; k < 16; k++) wt[k * 256 + t] = wsrc[k * 256 + t];
  __syncthreads();
  int p0 = stripe * 1024 + t;
  const float* xb = x + (size_t)b * CIN * HW + p0;
  float acc[16][4];
#pragma unroll
  for (int r = 0; r < 16; r++)
#pragma unroll
    for (int pp = 0; pp < 4; pp++) acc[r][pp] = 0.f;
  for (int ci = 0; ci < CIN; ci += 4) {
    float xv[4][4];
#pragma unroll
    for (int kk = 0; kk < 4; kk++)
#pragma unroll
      for (int pp = 0; pp < 4; pp++)
        xv[kk][pp] = xb[(size_t)(ci + kk) * HW + pp * 256];
#pragma unroll
    for (int r = 0; r < 16; r++) {
      floatx4 wv = *(const floatx4*)&wt[r * 256 + ci];
#pragma unroll
      for (int kk = 0; kk < 4; kk++)
#pragma unroll
        for (int pp = 0; pp < 4; pp++)
          acc[r][pp] += wv[kk] * xv[kk][pp];
    }
  }
  float* nb = nbuf + ((size_t)b * 384 + co0) * HW + p0;
#pragma unroll
  for (int r = 0; r < 16; r++)
#pragma unroll
    for (int pp = 0; pp < 4; pp++)
      nb[(size_t)r * HW + pp * 256] = acc[r][pp];
}

// ---------------- K2: layout + bf16 cast ----------------------------------------------
// Q[b][i][c]  = n1 flat (raw-reshape identity), cast.
// Kt[b][j][c] = n2[c][j]  (4096x128 transpose per b).
// Vt[b][c][j] = n3[j>>5][((j&31)<<7)+c].
__global__ __launch_bounds__(256) void k_layout(const float* __restrict__ nbuf,
    unsigned short* __restrict__ Q, unsigned short* __restrict__ Kt,
    unsigned short* __restrict__ Vt) {
  __shared__ float sm[2 * 4096];
  int bid = blockIdx.x;
  int t = threadIdx.x;
  if (bid < 1024) {                      // Q: straight cast
    size_t f = (size_t)bid * 2048 + (size_t)t * 8;
    int b = (int)(f >> 19);
    size_t r = f & 524287;
    const float* s = nbuf + (size_t)b * 384 * HW + r;
    union { unsigned short us[8]; uint4 v; } o;
#pragma unroll
    for (int k = 0; k < 8; k++) o.us[k] = f2bf(s[k]);
    *(uint4*)(Q + (size_t)b * 524288 + r) = o.v;
  } else if (bid < 1536) {               // Kt: 64x64 tile transpose
    int b2 = bid - 1024;
    int b = b2 >> 7;
    int rem = b2 & 127;
    int cht = rem >> 6;
    int pt = rem & 63;
    const float* n2 = nbuf + (size_t)b * 384 * HW + (size_t)(128 + cht * 64) * HW + pt * 64;
    for (int k = 0; k < 16; k++) {
      int idx = k * 256 + t;
      int rr = idx >> 6, pc = idx & 63;
      sm[rr * 65 + pc] = n2[(size_t)rr * HW + pc];
    }
    __syncthreads();
    int prow = t >> 2, seg = t & 3;
    union { unsigned short us[16]; uint4 v[2]; } o;
#pragma unroll
    for (int u = 0; u < 16; u++) o.us[u] = f2bf(sm[(seg * 16 + u) * 65 + prow]);
    unsigned short* d = Kt + (size_t)b * 524288 + (size_t)(pt * 64 + prow) * 128 + cht * 64 + seg * 16;
    *(uint4*)d = o.v[0];
    *(uint4*)(d + 8) = o.v[1];
  } else {                               // Vt
    int b3 = bid - 1536;
    int b = b3 >> 6;
    int chg = b3 & 63;
    const float* n3 = nbuf + (size_t)b * 384 * HW + (size_t)(256 + chg * 2) * HW;
    for (int k = 0; k < 32; k++) {
      int idx = k * 256 + t;
      sm[idx] = n3[idx];
    }
    __syncthreads();
    int c = t >> 1, half = t & 1;
    union { unsigned short us[32]; uint4 v[4]; } o;
#pragma unroll
    for (int u = 0; u < 32; u++) o.us[u] = f2bf(sm[half * 4096 + u * 128 + c]);
    unsigned short* d = Vt + ((size_t)b * 128 + c) * HW + chg * 64 + half * 32;
#pragma unroll
    for (int k = 0; k < 4; k++) *((uint4*)d + k) = o.v[k];
  }
}

// ---------------- K3: fused flash attention (bf16 MFMA, split-j) -----------------------
// Computes S^T[j][i] = Kt*Q^T tiles, online softmax over j, O[i][c] += P*V.
// grid: 1024 = b(4) x sp(4) x itile(64); block 256 (4 waves), wave owns 16 i.
__global__ __launch_bounds__(256, 4) void k_flash(const unsigned short* __restrict__ Q,
    const unsigned short* __restrict__ Kt, const unsigned short* __restrict__ Vt,
    float* __restrict__ Opart, float* __restrict__ ml) {
  __shared__ unsigned short KtS[64 * 128];   // [j][c] rows 256B, 16B-block xor-swizzled
  __shared__ unsigned short VtS[128 * 64];   // [c][j] rows 128B, swizzled
  __shared__ unsigned short PS[4 * 16 * 64]; // per-wave [i][j], 16B-granule swizzled
  int bid = blockIdx.x;
  int itile = bid & 63, sp = (bid >> 6) & 3, b = bid >> 8;
  int t = threadIdx.x;
  int w = t >> 6, lane = t & 63, l16 = lane & 15, quad = lane >> 4;
  int i0 = itile * 64;

  shortx8 qf[4];   // B-frags of Q for this wave's 16 i (resident whole kernel)
  {
    const unsigned short* qp = Q + ((size_t)b * HW + i0 + w * 16 + l16) * 128 + quad * 8;
#pragma unroll
    for (int ks = 0; ks < 4; ks++) qf[ks] = *(const shortx8*)(qp + ks * 32);
  }
  floatx4 O[8];
  floatx4 zf = {0.f, 0.f, 0.f, 0.f};
#pragma unroll
  for (int nt = 0; nt < 8; nt++) O[nt] = zf;
  float m_i = -1e30f, l_i = 0.f;
  const unsigned short* KtB = Kt + (size_t)b * HW * 128;
  const unsigned short* VtB = Vt + (size_t)b * 128 * HW;
  unsigned short* Pw = PS + w * 1024;

  for (int it = 0; it < JITERS; it++) {
    int j0 = sp * (HW / SPLIT) + it * JT;
    __syncthreads();                       // previous tile fully consumed
#pragma unroll
    for (int c4 = 0; c4 < 4; c4++) {       // stage Kt tile [64 j][128 c], swizzle at source
      int L = c4 * 256 + t;
      int r = L >> 4, xs = L & 15;
      int xx = xs ^ (r & 7);
      async16(KtB + (size_t)(j0 + r) * 128 + xx * 8, (char*)KtS + c4 * 4096 + w * 1024);
    }
#pragma unroll
    for (int c4 = 0; c4 < 4; c4++) {       // stage Vt tile [128 c][64 j]
      int L = c4 * 256 + t;
      int r = L >> 3, xs = L & 7;
      int xx = xs ^ (r & 7);
      async16(VtB + (size_t)r * HW + j0 + xx * 8, (char*)VtS + c4 * 4096 + w * 1024);
    }
    __syncthreads();                       // vmcnt drain + barrier

    // ---- QK: S^T[j][i], wave: all 64 j x its 16 i ----
    floatx4 S[4];
#pragma unroll
    for (int mt = 0; mt < 4; mt++) S[mt] = zf;
#pragma unroll
    for (int mt = 0; mt < 4; mt++) {
      int r = mt * 16 + l16;
#pragma unroll
      for (int ks = 0; ks < 4; ks++) {
        int xx = (quad + ks * 4) ^ (r & 7);
        shortx8 af = *(const shortx8*)((const char*)KtS + r * 256 + xx * 16);
        S[mt] = __builtin_amdgcn_mfma_f32_16x16x32_bf16(af, qf[ks], S[mt], 0, 0, 0);
      }
    }
    // ---- online softmax over j, per column i = l16 ----
    float tmax = S[0][0];
#pragma unroll
    for (int mt = 0; mt < 4; mt++)
#pragma unroll
      for (int rr = 0; rr < 4; rr++) tmax = fmaxf(tmax, S[mt][rr]);
    tmax = fmaxf(tmax, __shfl_xor(tmax, 16));
    tmax = fmaxf(tmax, __shfl_xor(tmax, 32));
    float mnew = fmaxf(m_i, tmax);
    float alpha = EXP2F((m_i - mnew) * L2E);
    float tsum = 0.f;
    float P[4][4];
#pragma unroll
    for (int mt = 0; mt < 4; mt++)
#pragma unroll
      for (int rr = 0; rr < 4; rr++) {
        float p = EXP2F((S[mt][rr] - mnew) * L2E);
        P[mt][rr] = p;
        tsum += p;
      }
    tsum += __shfl_xor(tsum, 16);
    tsum += __shfl_xor(tsum, 32);
    l_i = l_i * alpha + tsum;
    m_i = mnew;
    // O rows are i = quad*4+rr (C layout of PV) — fetch matching alpha via bpermute
    float ar[4];
#pragma unroll
    for (int rr = 0; rr < 4; rr++) ar[rr] = __shfl(alpha, quad * 4 + rr);
#pragma unroll
    for (int nt = 0; nt < 8; nt++)
#pragma unroll
      for (int rr = 0; rr < 4; rr++) O[nt][rr] *= ar[rr];
    // ---- P -> wave-private LDS [i][j] (C-layout -> A-layout transform) ----
#pragma unroll
    for (int mt = 0; mt < 4; mt++) {
      int jl = mt * 16 + quad * 4;
      unsigned lo = (unsigned)f2bf(P[mt][0]) | ((unsigned)f2bf(P[mt][1]) << 16);
      unsigned hi = (unsigned)f2bf(P[mt][2]) | ((unsigned)f2bf(P[mt][3]) << 16);
      uint2 val = make_uint2(lo, hi);
      int addr = l16 * 64 + (((jl >> 3) ^ (l16 & 7)) << 3) + (jl & 7);
      *(uint2*)(Pw + addr) = val;
    }
    __threadfence_block();                 // intra-wave LDS write->read ordering
    // ---- PV: O[i][c] += P[i][j] * V[j][c] ----
#pragma unroll
    for (int kt = 0; kt < 2; kt++) {
      int G0 = quad + kt * 4;
      shortx8 pf = *(const shortx8*)(Pw + l16 * 64 + ((G0 ^ (l16 & 7)) << 3));
#pragma unroll
      for (int nt = 0; nt < 8; nt++) {
        int r = nt * 16 + l16;
        int xx = G0 ^ (r & 7);
        shortx8 vf = *(const shortx8*)((const char*)VtS + r * 128 + xx * 16);
        O[nt] = __builtin_amdgcn_mfma_f32_16x16x32_bf16(pf, vf, O[nt], 0, 0, 0);
      }
    }
  }
  // epilogue: store partial O and (m,l)
  float* Ob = Opart + ((size_t)(sp * 4 + b) * HW + i0 + w * 16) * 128;
#pragma unroll
  for (int nt = 0; nt < 8; nt++)
#pragma unroll
    for (int rr = 0; rr < 4; rr++)
      Ob[(size_t)(quad * 4 + rr) * 128 + nt * 16 + l16] = O[nt][rr];
  if (quad == 0) {
    float2* mlp = (float2*)ml;
    mlp[(size_t)(sp * 4 + b) * HW + i0 + w * 16 + l16] = make_float2(m_i, l_i);
  }
}

// ---------------- K4: merge split-j partials -> res (flat == resmap layout) -----------
__global__ __launch_bounds__(256) void k_merge(const float* __restrict__ Opart,
    const float* __restrict__ ml, float* __restrict__ res) {
  size_t e = (size_t)blockIdx.x * 256 + threadIdx.x;  // float4 index
  int cq = (int)(e & 31);
  int i = (int)((e >> 5) & 4095);
  int b = (int)(e >> 17);
  const float2* mlp = (const float2*)ml;
  float m[SPLIT], l[SPLIT];
  float M = -1e30f;
#pragma unroll
  for (int s = 0; s < SPLIT; s++) {
    float2 st = mlp[(size_t)(s * 4 + b) * HW + i];
    m[s] = st.x; l[s] = st.y;
    M = fmaxf(M, m[s]);
  }
  float denom = 0.f;
  float wgt[SPLIT];
#pragma unroll
  for (int s = 0; s < SPLIT; s++) {
    float ws_ = EXP2F((m[s] - M) * L2E);
    wgt[s] = ws_;
    denom += l[s] * ws_;
  }
  float inv = 1.f / denom;
  floatx4 acc = {0.f, 0.f, 0.f, 0.f};
#pragma unroll
  for (int s = 0; s < SPLIT; s++) {
    floatx4 v = *(const floatx4*)(Opart + ((size_t)(s * 4 + b) * HW + i) * 128 + cq * 4);
    acc += v * (wgt[s] * inv);
  }
  *(floatx4*)(res + e * 4) = acc;
}

// ---------------- K5: conv4 (fp32) + BN(eval) + residual ------------------------------
__global__ __launch_bounds__(256) void k_out(const float* __restrict__ res,
    const float* __restrict__ w4, const float* __restrict__ gamma,
    const float* __restrict__ beta, const float* __restrict__ rmean,
    const float* __restrict__ rvar, const float* __restrict__ x,
    float* __restrict__ out) {
  __shared__ float wt[16 * 128];
  int bid = blockIdx.x;
  int cot = bid & 15;
  int stripe = (bid >> 4) & 3;
  int b = bid >> 6;
  int t = threadIdx.x;
  int co0 = cot * 16;
#pragma unroll
  for (int k = 0; k < 8; k++) wt[k * 256 + t] = w4[(size_t)co0 * 128 + k * 256 + t];
  __syncthreads();
  int p0 = stripe * 1024 + t;
  const float* rb = res + (size_t)b * 128 * HW + p0;
  float acc[16][4];
#pragma unroll
  for (int r = 0; r < 16; r++)
#pragma unroll
    for (int pp = 0; pp < 4; pp++) acc[r][pp] = 0.f;
  for (int ci = 0; ci < 128; ci += 4) {
    float xv[4][4];
#pragma unroll
    for (int kk = 0; kk < 4; kk++)
#pragma unroll
      for (int pp = 0; pp < 4; pp++)
        xv[kk][pp] = rb[(size_t)(ci + kk) * HW + pp * 256];
#pragma unroll
    for (int r = 0; r < 16; r++) {
      floatx4 wv = *(const floatx4*)&wt[r * 128 + ci];
#pragma unroll
      for (int kk = 0; kk < 4; kk++)
#pragma unroll
        for (int pp = 0; pp < 4; pp++)
          acc[r][pp] += wv[kk] * xv[kk][pp];
    }
  }
  const float* xb = x + ((size_t)b * 256 + co0) * HW + p0;
  float* ob = out + ((size_t)b * 256 + co0) * HW + p0;
#pragma unroll
  for (int r = 0; r < 16; r++) {
    int co = co0 + r;
    float g = gamma[co] * rsqrtf(rvar[co] + 1e-5f);
    float bb = beta[co] - rmean[co] * g;
#pragma unroll
    for (int pp = 0; pp < 4; pp++)
      ob[(size_t)r * HW + pp * 256] = acc[r][pp] * g + bb + xb[(size_t)r * HW + pp * 256];
  }
}

extern "C" void kernel_launch(void* const* d_in, const int* in_sizes, int n_in,
                              void* d_out, int out_size, void* d_ws, size_t ws_size,
                              hipStream_t stream) {
  const float* x     = (const float*)d_in[0];
  const float* w1    = (const float*)d_in[1];
  const float* w2    = (const float*)d_in[2];
  const float* w3    = (const float*)d_in[3];
  const float* w4    = (const float*)d_in[4];
  const float* gamma = (const float*)d_in[5];
  const float* beta  = (const float*)d_in[6];
  const float* rmean = (const float*)d_in[7];
  const float* rvar  = (const float*)d_in[8];
  float* out = (float*)d_out;
  char* ws = (char*)d_ws;

  // workspace layout (n-buffer overlaps Opart; n is dead before k_flash writes Opart)
  size_t off = (size_t)SPLIT * 4 * HW * 128 * 4;            // Opart: 32 MB
  float* nbuf  = (float*)ws;                                 // 25.2 MB (inside Opart region)
  float* Opart = (float*)ws;
  unsigned short* Q  = (unsigned short*)(ws + off); off += (size_t)4 * HW * 128 * 2;
  unsigned short* Kt = (unsigned short*)(ws + off); off += (size_t)4 * HW * 128 * 2;
  unsigned short* Vt = (unsigned short*)(ws + off); off += (size_t)4 * HW * 128 * 2;
  float* ml  = (float*)(ws + off); off += (size_t)SPLIT * 4 * HW * 2 * 4;
  float* res = (float*)(ws + off); off += (size_t)4 * HW * 128 * 4;
  if (ws_size < off) return;  // insufficient workspace: bail (validation will flag)

  k_proj  <<<384,  256, 0, stream>>>(x, w1, w2, w3, nbuf);
  k_layout<<<1792, 256, 0, stream>>>(nbuf, Q, Kt, Vt);
  k_flash <<<1024, 256, 0, stream>>>(Q, Kt, Vt, Opart, ml);
  k_merge <<<2048, 256, 0, stream>>>(Opart, ml, res);
  k_out   <<<256,  256, 0, stream>>>(res, w4, gamma, beta, rmean, rvar, x, out);
}

// Round 3
// 233.641 us; speedup vs baseline: 1.0036x; 1.0036x over previous
//
#include <hip/hip_runtime.h>
#include <cstdint>

#define BN 4
#define CIN 256
#define HALFC 128
#define HW 4096
#define SPLIT 4
#define JT 64
#define JITERS (HW / SPLIT / JT)   // 16

typedef float  floatx4 __attribute__((ext_vector_type(4)));
typedef short  shortx8 __attribute__((ext_vector_type(8)));

#if __has_builtin(__builtin_amdgcn_exp2f)
#define EXP2F(x) __builtin_amdgcn_exp2f(x)
#else
#define EXP2F(x) exp2f(x)
#endif
#define L2E 1.44269504088896f

__device__ __forceinline__ unsigned short f2bf(float f) {
  unsigned u = __float_as_uint(f);
  u += 0x7FFFu + ((u >> 16) & 1u);   // round-to-nearest-even
  return (unsigned short)(u >> 16);
}

__device__ __forceinline__ void async16(const void* g, void* l) {
  __builtin_amdgcn_global_load_lds((const __attribute__((address_space(1))) void*)g,
                                   (__attribute__((address_space(3))) void*)l, 16, 0, 0);
}

// ---------------- K1: QKV projection (fp32 accumulate, bf16 out) ----------------------
// grid: 768 = b(4) x stripe(4) x cot(48); 256 thr; thread: 8 co x 4 px.
// co<128 -> Q flat (n1 raw-reshape == Q), co>=128 -> n23 bf16 [b][256][4096].
__global__ __launch_bounds__(256) void k_proj(const float* __restrict__ x,
    const float* __restrict__ w1, const float* __restrict__ w2,
    const float* __restrict__ w3, unsigned short* __restrict__ Q,
    unsigned short* __restrict__ n23) {
  __shared__ float wt[8 * 256];
  int bid = blockIdx.x;
  int cot = bid % 48;
  int stripe = (bid / 48) & 3;
  int b = bid / 192;
  int t = threadIdx.x;
  int co0 = cot * 8;
  const float* wsrc = (co0 < 128) ? (w1 + (size_t)co0 * 256)
                    : (co0 < 256) ? (w2 + (size_t)(co0 - 128) * 256)
                                  : (w3 + (size_t)(co0 - 256) * 256);
#pragma unroll
  for (int k = 0; k < 8; k++) wt[k * 256 + t] = wsrc[k * 256 + t];
  __syncthreads();
  int p0 = stripe * 1024 + t;
  const float* xb = x + (size_t)b * CIN * HW + p0;
  float acc[8][4];
#pragma unroll
  for (int r = 0; r < 8; r++)
#pragma unroll
    for (int pp = 0; pp < 4; pp++) acc[r][pp] = 0.f;
  for (int ci = 0; ci < CIN; ci += 4) {
    float xv[4][4];
#pragma unroll
    for (int kk = 0; kk < 4; kk++)
#pragma unroll
      for (int pp = 0; pp < 4; pp++)
        xv[kk][pp] = xb[(size_t)(ci + kk) * HW + pp * 256];
#pragma unroll
    for (int r = 0; r < 8; r++) {
      floatx4 wv = *(const floatx4*)&wt[r * 256 + ci];
#pragma unroll
      for (int kk = 0; kk < 4; kk++)
#pragma unroll
        for (int pp = 0; pp < 4; pp++)
          acc[r][pp] += wv[kk] * xv[kk][pp];
    }
  }
#pragma unroll
  for (int r = 0; r < 8; r++) {
    int co = co0 + r;
    unsigned short* dst = (co < 128)
        ? (Q   + (size_t)b * 524288  + (size_t)co * HW + p0)
        : (n23 + (size_t)b * 1048576 + (size_t)(co - 128) * HW + p0);
#pragma unroll
    for (int pp = 0; pp < 4; pp++) dst[pp * 256] = f2bf(acc[r][pp]);
  }
}

// ---------------- K2: bf16 layout shuffles ---------------------------------------------
// Kt[b][j][c] = n2[c][j]  (transpose; n2 = n23 ch 0..127)
// Vt[b][c][j] = n3[j>>5][((j&31)<<7)+c]  (n3 = n23 ch 128..255)
__global__ __launch_bounds__(256) void k_layout(const unsigned short* __restrict__ n23,
    unsigned short* __restrict__ Kt, unsigned short* __restrict__ Vt) {
  __shared__ unsigned short sm[8192];   // Vt branch uses all 8192; Kt branch uses 64*65
  int bid = blockIdx.x;
  int t = threadIdx.x;
  if (bid < 512) {                       // Kt: 64x64 tile transpose
    int b = bid >> 7;
    int rem = bid & 127;
    int cht = rem >> 6;
    int pt = rem & 63;
    const unsigned short* n2 = n23 + (size_t)b * 1048576 + (size_t)(cht * 64) * HW + pt * 64;
#pragma unroll
    for (int k = 0; k < 16; k++) {
      int idx = k * 256 + t;
      int rr = idx >> 6, pc = idx & 63;
      sm[rr * 65 + pc] = n2[(size_t)rr * HW + pc];
    }
    __syncthreads();
    int prow = t >> 2, seg = t & 3;
    union { unsigned short us[16]; uint4 v[2]; } o;
#pragma unroll
    for (int u = 0; u < 16; u++) o.us[u] = sm[(seg * 16 + u) * 65 + prow];
    unsigned short* d = Kt + (size_t)b * 524288 + (size_t)(pt * 64 + prow) * 128 + cht * 64 + seg * 16;
    *(uint4*)d = o.v[0];
    *(uint4*)(d + 8) = o.v[1];
  } else {                               // Vt
    int b3 = bid - 512;
    int b = b3 >> 6;
    int chg = b3 & 63;
    const unsigned short* n3 = n23 + (size_t)b * 1048576 + 524288 + (size_t)(chg * 2) * HW;
#pragma unroll
    for (int k = 0; k < 32; k++) {
      int idx = k * 256 + t;
      sm[idx] = n3[idx];
    }
    __syncthreads();
    int c = t >> 1, half = t & 1;
    union { unsigned short us[32]; uint4 v[4]; } o;
#pragma unroll
    for (int u = 0; u < 32; u++) o.us[u] = sm[half * 4096 + u * 128 + c];
    unsigned short* d = Vt + ((size_t)b * 128 + c) * HW + chg * 64 + half * 32;
#pragma unroll
    for (int k = 0; k < 4; k++) *((uint4*)d + k) = o.v[k];
  }
}

// ---------------- K3: fused flash attention (bf16 MFMA, split-j) -----------------------
// Computes S^T[j][i] = Kt*Q^T tiles, online softmax over j, O[i][c] += P*V.
// grid: 1024 = b(4) x sp(4) x itile(64); block 256 (4 waves), wave owns 16 i.
__global__ __launch_bounds__(256, 4) void k_flash(const unsigned short* __restrict__ Q,
    const unsigned short* __restrict__ Kt, const unsigned short* __restrict__ Vt,
    float* __restrict__ Opart, float* __restrict__ ml) {
  __shared__ unsigned short KtS[64 * 128];   // [j][c] rows 256B, 16B-block xor-swizzled
  __shared__ unsigned short VtS[128 * 64];   // [c][j] rows 128B, swizzled
  __shared__ unsigned short PS[4 * 16 * 64]; // per-wave [i][j], 16B-granule swizzled
  int bid = blockIdx.x;
  int itile = bid & 63, sp = (bid >> 6) & 3, b = bid >> 8;
  int t = threadIdx.x;
  int w = t >> 6, lane = t & 63, l16 = lane & 15, quad = lane >> 4;
  int i0 = itile * 64;

  shortx8 qf[4];   // B-frags of Q for this wave's 16 i (resident whole kernel)
  {
    const unsigned short* qp = Q + ((size_t)b * HW + i0 + w * 16 + l16) * 128 + quad * 8;
#pragma unroll
    for (int ks = 0; ks < 4; ks++) qf[ks] = *(const shortx8*)(qp + ks * 32);
  }
  floatx4 O[8];
  floatx4 zf = {0.f, 0.f, 0.f, 0.f};
#pragma unroll
  for (int nt = 0; nt < 8; nt++) O[nt] = zf;
  float m_i = -1e30f, l_i = 0.f;
  const unsigned short* KtB = Kt + (size_t)b * HW * 128;
  const unsigned short* VtB = Vt + (size_t)b * 128 * HW;
  unsigned short* Pw = PS + w * 1024;

  for (int it = 0; it < JITERS; it++) {
    int j0 = sp * (HW / SPLIT) + it * JT;
    __syncthreads();                       // previous tile fully consumed
#pragma unroll
    for (int c4 = 0; c4 < 4; c4++) {       // stage Kt tile [64 j][128 c], swizzle at source
      int L = c4 * 256 + t;
      int r = L >> 4, xs = L & 15;
      int xx = xs ^ (r & 7);
      async16(KtB + (size_t)(j0 + r) * 128 + xx * 8, (char*)KtS + c4 * 4096 + w * 1024);
    }
#pragma unroll
    for (int c4 = 0; c4 < 4; c4++) {       // stage Vt tile [128 c][64 j]
      int L = c4 * 256 + t;
      int r = L >> 3, xs = L & 7;
      int xx = xs ^ (r & 7);
      async16(VtB + (size_t)r * HW + j0 + xx * 8, (char*)VtS + c4 * 4096 + w * 1024);
    }
    __syncthreads();                       // vmcnt drain + barrier

    // ---- QK: S^T[j][i], wave: all 64 j x its 16 i ----
    floatx4 S[4];
#pragma unroll
    for (int mt = 0; mt < 4; mt++) S[mt] = zf;
#pragma unroll
    for (int mt = 0; mt < 4; mt++) {
      int r = mt * 16 + l16;
#pragma unroll
      for (int ks = 0; ks < 4; ks++) {
        int xx = (quad + ks * 4) ^ (r & 7);
        shortx8 af = *(const shortx8*)((const char*)KtS + r * 256 + xx * 16);
        S[mt] = __builtin_amdgcn_mfma_f32_16x16x32_bf16(af, qf[ks], S[mt], 0, 0, 0);
      }
    }
    // ---- online softmax over j, per column i = l16 ----
    float tmax = S[0][0];
#pragma unroll
    for (int mt = 0; mt < 4; mt++)
#pragma unroll
      for (int rr = 0; rr < 4; rr++) tmax = fmaxf(tmax, S[mt][rr]);
    tmax = fmaxf(tmax, __shfl_xor(tmax, 16));
    tmax = fmaxf(tmax, __shfl_xor(tmax, 32));
    float mnew = fmaxf(m_i, tmax);
    float alpha = EXP2F((m_i - mnew) * L2E);
    float tsum = 0.f;
    float P[4][4];
#pragma unroll
    for (int mt = 0; mt < 4; mt++)
#pragma unroll
      for (int rr = 0; rr < 4; rr++) {
        float p = EXP2F((S[mt][rr] - mnew) * L2E);
        P[mt][rr] = p;
        tsum += p;
      }
    tsum += __shfl_xor(tsum, 16);
    tsum += __shfl_xor(tsum, 32);
    l_i = l_i * alpha + tsum;
    m_i = mnew;
    // O rows are i = quad*4+rr (C layout of PV) — fetch matching alpha via shfl
    float ar[4];
#pragma unroll
    for (int rr = 0; rr < 4; rr++) ar[rr] = __shfl(alpha, quad * 4 + rr);
#pragma unroll
    for (int nt = 0; nt < 8; nt++)
#pragma unroll
      for (int rr = 0; rr < 4; rr++) O[nt][rr] *= ar[rr];
    // ---- P -> wave-private LDS [i][j] (C-layout -> A-layout transform) ----
#pragma unroll
    for (int mt = 0; mt < 4; mt++) {
      int jl = mt * 16 + quad * 4;
      unsigned lo = (unsigned)f2bf(P[mt][0]) | ((unsigned)f2bf(P[mt][1]) << 16);
      unsigned hi = (unsigned)f2bf(P[mt][2]) | ((unsigned)f2bf(P[mt][3]) << 16);
      uint2 val = make_uint2(lo, hi);
      int addr = l16 * 64 + (((jl >> 3) ^ (l16 & 7)) << 3) + (jl & 7);
      *(uint2*)(Pw + addr) = val;
    }
    __threadfence_block();                 // intra-wave LDS write->read ordering
    // ---- PV: O[i][c] += P[i][j] * V[j][c] ----
#pragma unroll
    for (int kt = 0; kt < 2; kt++) {
      int G0 = quad + kt * 4;
      shortx8 pf = *(const shortx8*)(Pw + l16 * 64 + ((G0 ^ (l16 & 7)) << 3));
#pragma unroll
      for (int nt = 0; nt < 8; nt++) {
        int r = nt * 16 + l16;
        int xx = G0 ^ (r & 7);
        shortx8 vf = *(const shortx8*)((const char*)VtS + r * 128 + xx * 16);
        O[nt] = __builtin_amdgcn_mfma_f32_16x16x32_bf16(pf, vf, O[nt], 0, 0, 0);
      }
    }
  }
  // epilogue: store partial O and (m,l)
  float* Ob = Opart + ((size_t)(sp * 4 + b) * HW + i0 + w * 16) * 128;
#pragma unroll
  for (int nt = 0; nt < 8; nt++)
#pragma unroll
    for (int rr = 0; rr < 4; rr++)
      Ob[(size_t)(quad * 4 + rr) * 128 + nt * 16 + l16] = O[nt][rr];
  if (quad == 0) {
    float2* mlp = (float2*)ml;
    mlp[(size_t)(sp * 4 + b) * HW + i0 + w * 16 + l16] = make_float2(m_i, l_i);
  }
}

// ---------------- K4: merge split-j partials -> res (flat == resmap layout) -----------
__global__ __launch_bounds__(256) void k_merge(const float* __restrict__ Opart,
    const float* __restrict__ ml, float* __restrict__ res) {
  size_t e = (size_t)blockIdx.x * 256 + threadIdx.x;  // float4 index
  int cq = (int)(e & 31);
  int i = (int)((e >> 5) & 4095);
  int b = (int)(e >> 17);
  const float2* mlp = (const float2*)ml;
  float m[SPLIT], l[SPLIT];
  float M = -1e30f;
#pragma unroll
  for (int s = 0; s < SPLIT; s++) {
    float2 st = mlp[(size_t)(s * 4 + b) * HW + i];
    m[s] = st.x; l[s] = st.y;
    M = fmaxf(M, m[s]);
  }
  float denom = 0.f;
  float wgt[SPLIT];
#pragma unroll
  for (int s = 0; s < SPLIT; s++) {
    float ws_ = EXP2F((m[s] - M) * L2E);
    wgt[s] = ws_;
    denom += l[s] * ws_;
  }
  float inv = 1.f / denom;
  floatx4 acc = {0.f, 0.f, 0.f, 0.f};
#pragma unroll
  for (int s = 0; s < SPLIT; s++) {
    floatx4 v = *(const floatx4*)(Opart + ((size_t)(s * 4 + b) * HW + i) * 128 + cq * 4);
    acc += v * (wgt[s] * inv);
  }
  *(floatx4*)(res + e * 4) = acc;
}

// ---------------- K5: conv4 (fp32) + BN(eval) + residual ------------------------------
__global__ __launch_bounds__(256) void k_out(const float* __restrict__ res,
    const float* __restrict__ w4, const float* __restrict__ gamma,
    const float* __restrict__ beta, const float* __restrict__ rmean,
    const float* __restrict__ rvar, const float* __restrict__ x,
    float* __restrict__ out) {
  __shared__ float wt[16 * 128];
  int bid = blockIdx.x;
  int cot = bid & 15;
  int stripe = (bid >> 4) & 3;
  int b = bid >> 6;
  int t = threadIdx.x;
  int co0 = cot * 16;
#pragma unroll
  for (int k = 0; k < 8; k++) wt[k * 256 + t] = w4[(size_t)co0 * 128 + k * 256 + t];
  __syncthreads();
  int p0 = stripe * 1024 + t;
  const float* rb = res + (size_t)b * 128 * HW + p0;
  float acc[16][4];
#pragma unroll
  for (int r = 0; r < 16; r++)
#pragma unroll
    for (int pp = 0; pp < 4; pp++) acc[r][pp] = 0.f;
  for (int ci = 0; ci < 128; ci += 4) {
    float xv[4][4];
#pragma unroll
    for (int kk = 0; kk < 4; kk++)
#pragma unroll
      for (int pp = 0; pp < 4; pp++)
        xv[kk][pp] = rb[(size_t)(ci + kk) * HW + pp * 256];
#pragma unroll
    for (int r = 0; r < 16; r++) {
      floatx4 wv = *(const floatx4*)&wt[r * 128 + ci];
#pragma unroll
      for (int kk = 0; kk < 4; kk++)
#pragma unroll
        for (int pp = 0; pp < 4; pp++)
          acc[r][pp] += wv[kk] * xv[kk][pp];
    }
  }
  const float* xb = x + ((size_t)b * 256 + co0) * HW + p0;
  float* ob = out + ((size_t)b * 256 + co0) * HW + p0;
#pragma unroll
  for (int r = 0; r < 16; r++) {
    int co = co0 + r;
    float g = gamma[co] * rsqrtf(rvar[co] + 1e-5f);
    float bb = beta[co] - rmean[co] * g;
#pragma unroll
    for (int pp = 0; pp < 4; pp++)
      ob[(size_t)r * HW + pp * 256] = acc[r][pp] * g + bb + xb[(size_t)r * HW + pp * 256];
  }
}

extern "C" void kernel_launch(void* const* d_in, const int* in_sizes, int n_in,
                              void* d_out, int out_size, void* d_ws, size_t ws_size,
                              hipStream_t stream) {
  const float* x     = (const float*)d_in[0];
  const float* w1    = (const float*)d_in[1];
  const float* w2    = (const float*)d_in[2];
  const float* w3    = (const float*)d_in[3];
  const float* w4    = (const float*)d_in[4];
  const float* gamma = (const float*)d_in[5];
  const float* beta  = (const float*)d_in[6];
  const float* rmean = (const float*)d_in[7];
  const float* rvar  = (const float*)d_in[8];
  float* out = (float*)d_out;
  char* ws = (char*)d_ws;

  // workspace layout (n23 bf16 overlaps Opart; n23 dead before k_flash writes Opart)
  size_t off = (size_t)SPLIT * 4 * HW * 128 * 4;            // Opart: 32 MB
  unsigned short* n23 = (unsigned short*)ws;                 // 8.4 MB (inside Opart region)
  float* Opart = (float*)ws;
  unsigned short* Q  = (unsigned short*)(ws + off); off += (size_t)4 * HW * 128 * 2;
  unsigned short* Kt = (unsigned short*)(ws + off); off += (size_t)4 * HW * 128 * 2;
  unsigned short* Vt = (unsigned short*)(ws + off); off += (size_t)4 * HW * 128 * 2;
  float* ml  = (float*)(ws + off); off += (size_t)SPLIT * 4 * HW * 2 * 4;
  float* res = (float*)(ws + off); off += (size_t)4 * HW * 128 * 4;
  if (ws_size < off) return;  // insufficient workspace: bail (validation will flag)

  k_proj  <<<768,  256, 0, stream>>>(x, w1, w2, w3, Q, n23);
  k_layout<<<768,  256, 0, stream>>>(n23, Kt, Vt);
  k_flash <<<1024, 256, 0, stream>>>(Q, Kt, Vt, Opart, ml);
  k_merge <<<2048, 256, 0, stream>>>(Opart, ml, res);
  k_out   <<<256,  256, 0, stream>>>(res, w4, gamma, beta, rmean, rvar, x, out);
}